// Round 6
// baseline (5391.802 us; speedup 1.0000x reference)
//
#include <hip/hip_runtime.h>
#include <math.h>

#define NB 32
#define LSTR 260   // lat row stride (floats), 1040B = 65*16
#define WSTR 264   // wsh row stride, 1056B = 66*16
#define PSTR 212   // pbuf row stride, 848B = 53*16

__device__ __forceinline__ float softplus_f(float v) {
    return v > 0.f ? v + log1pf(expf(-v)) : log1pf(expf(v));
}

// p points at this row's 97 spline params in LDS (exclusively owned here).
// Overwrites p[0..63] with normalized bin widths/heights as scratch.
__device__ float rqs_eval(float x, float* p) {
    const float RMIN = -3.0f;
    const float total = 6.0f - 32.0f * 1e-5f;     // (RANGE - N_BINS*MIN_BIN)
    const float OFF = 0.54130903f;                // log(exp(1-1e-5)-1)

    float mw = -INFINITY, mh = -INFINITY;
    #pragma unroll
    for (int i = 0; i < NB; ++i) {
        mw = fmaxf(mw, p[i]);
        mh = fmaxf(mh, p[NB + i]);
    }
    float swd = 0.f, shd = 0.f;
    #pragma unroll
    for (int i = 0; i < NB; ++i) {
        swd += expf(p[i] - mw);
        shd += expf(p[NB + i] - mh);
    }
    float sw_scale = total / swd;
    float sh_scale = total / shd;

    float cumw = 0.f;
    int cnt = 0;
    #pragma unroll
    for (int i = 0; i < NB; ++i) {
        float wi = expf(p[i] - mw) * sw_scale + 1e-5f;
        p[i] = wi;
        cumw += wi;
        cnt += (x >= RMIN + cumw) ? 1 : 0;
        float hi = expf(p[NB + i] - mh) * sh_scale + 1e-5f;
        p[NB + i] = hi;
    }
    int idx = cnt < 31 ? cnt : 31;

    float cw = 0.f, ch = 0.f;
    #pragma unroll
    for (int i = 0; i < NB; ++i) {
        if (i < idx) { cw += p[i]; ch += p[NB + i]; }
    }
    float wk = p[idx], hk = p[NB + idx];
    float dk  = softplus_f(p[2 * NB + idx] + OFF) + 1e-5f;
    float dk1 = softplus_f(p[2 * NB + idx + 1] + OFF) + 1e-5f;

    float xk = RMIN + cw, yk = RMIN + ch;
    float z = (x - xk) / wk;
    z = fminf(fmaxf(z, 0.f), 1.f);
    float s = hk / wk;
    float z1 = z * (1.f - z);
    float num = hk * (s * z * z + dk * z1);
    float den = s + (dk1 + dk - 2.f * s) * z1;
    float y = yk + num / den;
    return (x < -3.0f || x > 3.0f) ? x : y;
}

__global__ __launch_bounds__(256) void condflow_kernel(
    const float* __restrict__ cond, const float* __restrict__ t_in,
    const float* __restrict__ w1, const float* __restrict__ b1,
    const float* __restrict__ w2, const float* __restrict__ b2,
    const float* __restrict__ sw, const float* __restrict__ sb,
    const float* __restrict__ aw, const float* __restrict__ ab,
    float* __restrict__ out)
{
    __shared__ float lat[32][LSTR];    // 33280 B
    __shared__ float wsh[16][WSTR];    // 16896 B
    __shared__ float pbuf[32][PSTR];   // 27136 B  (cond tile, then spline params 2 layers)
    __shared__ float sa_s[32][4];      // 512 B    -> total ~76 KB => 2 blocks/CU

    const int t = threadIdx.x;
    const int row0 = blockIdx.x * 32;

    // ---- stage cond tile [32][64] into pbuf[r][0..63] ----
    #pragma unroll
    for (int it = 0; it < 2; ++it) {
        int idx = it * 256 + t;            // 512 float4s
        int r = idx >> 4;
        int c4 = idx & 15;
        float4 v = *reinterpret_cast<const float4*>(cond + (size_t)(row0 + r) * 64 + c4 * 4);
        *reinterpret_cast<float4*>(&pbuf[r][c4 * 4]) = v;
    }

    const int rg = t >> 5;        // 0..7 -> rows rg*4..+3
    const int tc = t & 31;        // 0..31
    const int r0 = rg * 4;
    const int cA = tc * 4;        // contiguous 16B-stride B-reads: conflict-free
    const int cB = 128 + tc * 4;

    float acc[4][8];

    // ---- GEMM1: lat = relu(cond @ w1 + b1), K=64 (4 chunks of 16) ----
    #pragma unroll
    for (int j = 0; j < 4; ++j)
        #pragma unroll
        for (int i = 0; i < 8; ++i) acc[j][i] = 0.f;

    for (int kc = 0; kc < 4; ++kc) {
        __syncthreads();
        #pragma unroll
        for (int it = 0; it < 4; ++it) {
            int idx = it * 256 + t;        // 1024 float4 = 16x256
            int kk = idx >> 6;
            int c4 = idx & 63;
            float4 v = *reinterpret_cast<const float4*>(w1 + (size_t)(kc * 16 + kk) * 256 + c4 * 4);
            *reinterpret_cast<float4*>(&wsh[kk][c4 * 4]) = v;
        }
        __syncthreads();
        #pragma unroll
        for (int k4 = 0; k4 < 4; ++k4) {
            float a4[4][4];
            #pragma unroll
            for (int j = 0; j < 4; ++j)
                *reinterpret_cast<float4*>(&a4[j][0]) =
                    *reinterpret_cast<const float4*>(&pbuf[r0 + j][kc * 16 + k4 * 4]);
            #pragma unroll
            for (int s = 0; s < 4; ++s) {
                float bA[4], bB[4];
                *reinterpret_cast<float4*>(bA) = *reinterpret_cast<const float4*>(&wsh[k4 * 4 + s][cA]);
                *reinterpret_cast<float4*>(bB) = *reinterpret_cast<const float4*>(&wsh[k4 * 4 + s][cB]);
                #pragma unroll
                for (int j = 0; j < 4; ++j)
                    #pragma unroll
                    for (int i = 0; i < 4; ++i) {
                        acc[j][i]     = fmaf(a4[j][s], bA[i], acc[j][i]);
                        acc[j][4 + i] = fmaf(a4[j][s], bB[i], acc[j][4 + i]);
                    }
            }
        }
    }
    __syncthreads();
    {
        float bA[4], bB[4];
        *reinterpret_cast<float4*>(bA) = *reinterpret_cast<const float4*>(b1 + cA);
        *reinterpret_cast<float4*>(bB) = *reinterpret_cast<const float4*>(b1 + cB);
        #pragma unroll
        for (int j = 0; j < 4; ++j)
            #pragma unroll
            for (int i = 0; i < 4; ++i) {
                lat[r0 + j][cA + i] = fmaxf(acc[j][i] + bA[i], 0.f);
                lat[r0 + j][cB + i] = fmaxf(acc[j][4 + i] + bB[i], 0.f);
            }
    }

    // ---- GEMM2: lat = relu(lat @ w2 + b2), K=256 (16 chunks), in place ----
    #pragma unroll
    for (int j = 0; j < 4; ++j)
        #pragma unroll
        for (int i = 0; i < 8; ++i) acc[j][i] = 0.f;

    for (int kc = 0; kc < 16; ++kc) {
        __syncthreads();
        #pragma unroll
        for (int it = 0; it < 4; ++it) {
            int idx = it * 256 + t;
            int kk = idx >> 6;
            int c4 = idx & 63;
            float4 v = *reinterpret_cast<const float4*>(w2 + (size_t)(kc * 16 + kk) * 256 + c4 * 4);
            *reinterpret_cast<float4*>(&wsh[kk][c4 * 4]) = v;
        }
        __syncthreads();
        #pragma unroll
        for (int k4 = 0; k4 < 4; ++k4) {
            float a4[4][4];
            #pragma unroll
            for (int j = 0; j < 4; ++j)
                *reinterpret_cast<float4*>(&a4[j][0]) =
                    *reinterpret_cast<const float4*>(&lat[r0 + j][kc * 16 + k4 * 4]);
            #pragma unroll
            for (int s = 0; s < 4; ++s) {
                float bA[4], bB[4];
                *reinterpret_cast<float4*>(bA) = *reinterpret_cast<const float4*>(&wsh[k4 * 4 + s][cA]);
                *reinterpret_cast<float4*>(bB) = *reinterpret_cast<const float4*>(&wsh[k4 * 4 + s][cB]);
                #pragma unroll
                for (int j = 0; j < 4; ++j)
                    #pragma unroll
                    for (int i = 0; i < 4; ++i) {
                        acc[j][i]     = fmaf(a4[j][s], bA[i], acc[j][i]);
                        acc[j][4 + i] = fmaf(a4[j][s], bB[i], acc[j][4 + i]);
                    }
            }
        }
    }
    __syncthreads();                       // all lat reads done before in-place overwrite
    {
        float bA[4], bB[4];
        *reinterpret_cast<float4*>(bA) = *reinterpret_cast<const float4*>(b2 + cA);
        *reinterpret_cast<float4*>(bB) = *reinterpret_cast<const float4*>(b2 + cB);
        #pragma unroll
        for (int j = 0; j < 4; ++j)
            #pragma unroll
            for (int i = 0; i < 4; ++i) {
                lat[r0 + j][cA + i] = fmaxf(acc[j][i] + bA[i], 0.f);
                lat[r0 + j][cB + i] = fmaxf(acc[j][4 + i] + bB[i], 0.f);
            }
    }
    __syncthreads();

    // ---- sa = lat @ aff_w + aff_b; x0 = t*exp(sa1)+sa0 ----
    if (t < 128) {
        int r = t >> 2;
        int cc = t & 3;
        float s = 0.f;
        for (int k = 0; k < 256; k += 4) {
            float4 a = *reinterpret_cast<const float4*>(&lat[r][k]);
            s = fmaf(a.x, aw[(k + 0) * 4 + cc], s);
            s = fmaf(a.y, aw[(k + 1) * 4 + cc], s);
            s = fmaf(a.z, aw[(k + 2) * 4 + cc], s);
            s = fmaf(a.w, aw[(k + 3) * 4 + cc], s);
        }
        sa_s[r][cc] = s + ab[cc];
    }
    __syncthreads();
    float x = 0.f;
    if (t < 32) x = t_in[row0 + t] * expf(sa_s[t][1]) + sa_s[t][0];

    // ---- spline: 2 passes, each computes params for 2 layers (hi at cols 0..96, lo at 104..200) ----
    const int rgs = t / 26;                // 0..7 for t<208
    const int cts = t - rgs * 26;          // 0..25
    const bool act = (t < 208);
    const int rs0 = rgs * 4;
    const int sA = cts * 4;                // 0..100
    const int sB = 104 + cts * 4;          // 104..204

    for (int pass = 0; pass < 2; ++pass) {
        const int hi = (pass == 0) ? 3 : 1;
        const int lo = hi - 1;

        #pragma unroll
        for (int j = 0; j < 4; ++j)
            #pragma unroll
            for (int i = 0; i < 8; ++i) acc[j][i] = 0.f;

        for (int kc = 0; kc < 16; ++kc) {
            __syncthreads();
            for (int idx = t; idx < 16 * 208; idx += 256) {
                int kk = idx / 208;
                int c = idx - kk * 208;
                int layer = (c < 104) ? hi : lo;
                int cl = (c < 104) ? c : c - 104;
                float v = 0.f;
                if (cl < 97)
                    v = sw[(size_t)(layer * 256 + kc * 16 + kk) * 97 + cl];
                wsh[kk][c] = v;
            }
            __syncthreads();
            if (act) {
                #pragma unroll
                for (int k4 = 0; k4 < 4; ++k4) {
                    float a4[4][4];
                    #pragma unroll
                    for (int j = 0; j < 4; ++j)
                        *reinterpret_cast<float4*>(&a4[j][0]) =
                            *reinterpret_cast<const float4*>(&lat[rs0 + j][kc * 16 + k4 * 4]);
                    #pragma unroll
                    for (int s = 0; s < 4; ++s) {
                        float bA[4], bB[4];
                        *reinterpret_cast<float4*>(bA) = *reinterpret_cast<const float4*>(&wsh[k4 * 4 + s][sA]);
                        *reinterpret_cast<float4*>(bB) = *reinterpret_cast<const float4*>(&wsh[k4 * 4 + s][sB]);
                        #pragma unroll
                        for (int j = 0; j < 4; ++j)
                            #pragma unroll
                            for (int i = 0; i < 4; ++i) {
                                acc[j][i]     = fmaf(a4[j][s], bA[i], acc[j][i]);
                                acc[j][4 + i] = fmaf(a4[j][s], bB[i], acc[j][4 + i]);
                            }
                    }
                }
            }
        }
        __syncthreads();
        if (act) {
            #pragma unroll
            for (int j = 0; j < 4; ++j)
                #pragma unroll
                for (int i = 0; i < 4; ++i) {
                    int clA = sA + i;                 // layer hi col
                    if (clA < 97) pbuf[rs0 + j][clA] = acc[j][i] + sb[hi * 97 + clA];
                    int clB = sB + i - 104;           // layer lo col
                    if (clB < 97) pbuf[rs0 + j][104 + clB] = acc[j][4 + i] + sb[lo * 97 + clB];
                }
        }
        __syncthreads();
        if (t < 32) {
            x = rqs_eval(x, &pbuf[t][0]);      // layer hi first (chain order)
            x = rqs_eval(x, &pbuf[t][104]);    // then layer lo
        }
    }

    // ---- f2 affine + normal CDF ----
    if (t < 32) {
        float xf = x * expf(sa_s[t][3]) + sa_s[t][2];
        out[row0 + t] = 0.5f * (1.0f + erff(xf * 0.70710678118f));
    }
}

extern "C" void kernel_launch(void* const* d_in, const int* in_sizes, int n_in,
                              void* d_out, int out_size, void* d_ws, size_t ws_size,
                              hipStream_t stream) {
    const float* cond = (const float*)d_in[0];
    const float* t_in = (const float*)d_in[1];
    const float* w1   = (const float*)d_in[2];
    const float* b1   = (const float*)d_in[3];
    const float* w2   = (const float*)d_in[4];
    const float* b2   = (const float*)d_in[5];
    const float* sw   = (const float*)d_in[6];
    const float* sb   = (const float*)d_in[7];
    const float* aw   = (const float*)d_in[8];
    const float* ab   = (const float*)d_in[9];
    float* out = (float*)d_out;

    const int B = out_size;            // 262144
    const int nblocks = B / 32;        // 8192
    condflow_kernel<<<dim3(nblocks), dim3(256), 0, stream>>>(
        cond, t_in, w1, b1, w2, b2, sw, sb, aw, ab, out);
}

// Round 7
// 2176.222 us; speedup vs baseline: 2.4776x; 2.4776x over previous
//
#include <hip/hip_runtime.h>
#include <math.h>

#define NB 32
#define LSTR 260   // lat row stride (floats)
#define WSTR 264   // wsh row stride
#define PSTR 212   // pbuf row stride (848B = 53*16, 16B-aligned rows)

__device__ __forceinline__ float softplus_f(float v) {
    return v > 0.f ? v + log1pf(expf(-v)) : log1pf(expf(v));
}

// p -> this row's 97 spline params in LDS (exclusively owned by caller thread).
// Overwrites p[0..63] with normalized widths/heights as scratch.
__device__ float rqs_eval(float x, float* p) {
    const float RMIN = -3.0f;
    const float total = 6.0f - 32.0f * 1e-5f;
    const float OFF = 0.54130903f;                // log(exp(1-1e-5)-1)

    float mw = -INFINITY, mh = -INFINITY;
    #pragma unroll
    for (int i = 0; i < NB; ++i) {
        mw = fmaxf(mw, p[i]);
        mh = fmaxf(mh, p[NB + i]);
    }
    float swd = 0.f, shd = 0.f;
    #pragma unroll
    for (int i = 0; i < NB; ++i) {
        swd += expf(p[i] - mw);
        shd += expf(p[NB + i] - mh);
    }
    float sw_scale = total / swd;
    float sh_scale = total / shd;

    float cumw = 0.f;
    int cnt = 0;
    #pragma unroll
    for (int i = 0; i < NB; ++i) {
        float wi = expf(p[i] - mw) * sw_scale + 1e-5f;
        p[i] = wi;
        cumw += wi;
        cnt += (x >= RMIN + cumw) ? 1 : 0;
        float hi = expf(p[NB + i] - mh) * sh_scale + 1e-5f;
        p[NB + i] = hi;
    }
    int idx = cnt < 31 ? cnt : 31;

    float cw = 0.f, ch = 0.f;
    #pragma unroll
    for (int i = 0; i < NB; ++i) {
        if (i < idx) { cw += p[i]; ch += p[NB + i]; }
    }
    float wk = p[idx], hk = p[NB + idx];
    float dk  = softplus_f(p[2 * NB + idx] + OFF) + 1e-5f;
    float dk1 = softplus_f(p[2 * NB + idx + 1] + OFF) + 1e-5f;

    float xk = RMIN + cw, yk = RMIN + ch;
    float z = (x - xk) / wk;
    z = fminf(fmaxf(z, 0.f), 1.f);
    float s = hk / wk;
    float z1 = z * (1.f - z);
    float num = hk * (s * z * z + dk * z1);
    float den = s + (dk1 + dk - 2.f * s) * z1;
    float y = yk + num / den;
    return (x < -3.0f || x > 3.0f) ? x : y;
}

__global__ __launch_bounds__(512) void condflow_kernel(
    const float* __restrict__ cond, const float* __restrict__ t_in,
    const float* __restrict__ w1, const float* __restrict__ b1,
    const float* __restrict__ w2, const float* __restrict__ b2,
    const float* __restrict__ sw, const float* __restrict__ sb,
    const float* __restrict__ aw, const float* __restrict__ ab,
    float* __restrict__ out)
{
    __shared__ float lat[64][LSTR];    // 66560 B
    __shared__ float wsh[16][WSTR];    // 16896 B  (weight chunk; also aff_w flat)
    __shared__ float pbuf[64][PSTR];   // 54272 B  (cond tile, then 2-layer spline params)
    __shared__ float sa_s[64][4];      // 1024 B   -> total ~135.5 KB, 1 block/CU, 8 waves

    const int t  = threadIdx.x;
    const int row0 = blockIdx.x * 64;
    const int rg = t >> 6;        // wave id = row-group (A-reads broadcast per wave)
    const int tc = t & 63;
    const int r0 = rg * 8;        // 8 rows per thread
    const int cA = tc * 4;        // 4 cols per thread, 64*16B contiguous B-reads

    // ---- stage cond tile [64][64] into pbuf ----
    #pragma unroll
    for (int it = 0; it < 2; ++it) {
        int idx = it * 512 + t;
        int r = idx >> 4, c4 = idx & 15;
        *reinterpret_cast<float4*>(&pbuf[r][c4 * 4]) =
            *reinterpret_cast<const float4*>(cond + (size_t)(row0 + r) * 64 + c4 * 4);
    }

    float acc[8][4];
    float4 pre0, pre1;

    // ================= GEMM1: lat = relu(cond @ w1 + b1), K=64 =================
    #pragma unroll
    for (int j = 0; j < 8; ++j)
        #pragma unroll
        for (int i = 0; i < 4; ++i) acc[j][i] = 0.f;

    pre0 = *reinterpret_cast<const float4*>(w1 + (size_t)(t >> 6) * 256 + (t & 63) * 4);
    pre1 = *reinterpret_cast<const float4*>(w1 + (size_t)(8 + (t >> 6)) * 256 + (t & 63) * 4);

    for (int kc = 0; kc < 4; ++kc) {
        __syncthreads();                             // prev chunk's reads done
        *reinterpret_cast<float4*>(&wsh[t >> 6][(t & 63) * 4]) = pre0;
        *reinterpret_cast<float4*>(&wsh[8 + (t >> 6)][(t & 63) * 4]) = pre1;
        __syncthreads();                             // chunk visible
        if (kc < 3) {
            pre0 = *reinterpret_cast<const float4*>(w1 + (size_t)((kc + 1) * 16 + (t >> 6)) * 256 + (t & 63) * 4);
            pre1 = *reinterpret_cast<const float4*>(w1 + (size_t)((kc + 1) * 16 + 8 + (t >> 6)) * 256 + (t & 63) * 4);
        }
        #pragma unroll
        for (int k4 = 0; k4 < 4; ++k4) {
            float a[8][4];
            #pragma unroll
            for (int j = 0; j < 8; ++j)
                *reinterpret_cast<float4*>(&a[j][0]) =
                    *reinterpret_cast<const float4*>(&pbuf[r0 + j][kc * 16 + k4 * 4]);
            #pragma unroll
            for (int s = 0; s < 4; ++s) {
                float b[4];
                *reinterpret_cast<float4*>(b) = *reinterpret_cast<const float4*>(&wsh[k4 * 4 + s][cA]);
                #pragma unroll
                for (int j = 0; j < 8; ++j)
                    #pragma unroll
                    for (int i = 0; i < 4; ++i)
                        acc[j][i] = fmaf(a[j][s], b[i], acc[j][i]);
            }
        }
    }
    {   // write latent1 (no reader until after 2 more barriers)
        float b4[4];
        *reinterpret_cast<float4*>(b4) = *reinterpret_cast<const float4*>(b1 + cA);
        #pragma unroll
        for (int j = 0; j < 8; ++j) {
            float4 v;
            v.x = fmaxf(acc[j][0] + b4[0], 0.f);
            v.y = fmaxf(acc[j][1] + b4[1], 0.f);
            v.z = fmaxf(acc[j][2] + b4[2], 0.f);
            v.w = fmaxf(acc[j][3] + b4[3], 0.f);
            *reinterpret_cast<float4*>(&lat[r0 + j][cA]) = v;
        }
    }

    // ================= GEMM2: lat = relu(lat @ w2 + b2), K=256, in place ========
    #pragma unroll
    for (int j = 0; j < 8; ++j)
        #pragma unroll
        for (int i = 0; i < 4; ++i) acc[j][i] = 0.f;

    pre0 = *reinterpret_cast<const float4*>(w2 + (size_t)(t >> 6) * 256 + (t & 63) * 4);
    pre1 = *reinterpret_cast<const float4*>(w2 + (size_t)(8 + (t >> 6)) * 256 + (t & 63) * 4);

    for (int kc = 0; kc < 16; ++kc) {
        __syncthreads();
        *reinterpret_cast<float4*>(&wsh[t >> 6][(t & 63) * 4]) = pre0;
        *reinterpret_cast<float4*>(&wsh[8 + (t >> 6)][(t & 63) * 4]) = pre1;
        __syncthreads();
        if (kc < 15) {
            pre0 = *reinterpret_cast<const float4*>(w2 + (size_t)((kc + 1) * 16 + (t >> 6)) * 256 + (t & 63) * 4);
            pre1 = *reinterpret_cast<const float4*>(w2 + (size_t)((kc + 1) * 16 + 8 + (t >> 6)) * 256 + (t & 63) * 4);
        }
        #pragma unroll
        for (int k4 = 0; k4 < 4; ++k4) {
            float a[8][4];
            #pragma unroll
            for (int j = 0; j < 8; ++j)
                *reinterpret_cast<float4*>(&a[j][0]) =
                    *reinterpret_cast<const float4*>(&lat[r0 + j][kc * 16 + k4 * 4]);
            #pragma unroll
            for (int s = 0; s < 4; ++s) {
                float b[4];
                *reinterpret_cast<float4*>(b) = *reinterpret_cast<const float4*>(&wsh[k4 * 4 + s][cA]);
                #pragma unroll
                for (int j = 0; j < 8; ++j)
                    #pragma unroll
                    for (int i = 0; i < 4; ++i)
                        acc[j][i] = fmaf(a[j][s], b[i], acc[j][i]);
            }
        }
    }
    __syncthreads();                                 // all lat reads done before overwrite
    {
        float b4[4];
        *reinterpret_cast<float4*>(b4) = *reinterpret_cast<const float4*>(b2 + cA);
        #pragma unroll
        for (int j = 0; j < 8; ++j) {
            float4 v;
            v.x = fmaxf(acc[j][0] + b4[0], 0.f);
            v.y = fmaxf(acc[j][1] + b4[1], 0.f);
            v.z = fmaxf(acc[j][2] + b4[2], 0.f);
            v.w = fmaxf(acc[j][3] + b4[3], 0.f);
            *reinterpret_cast<float4*>(&lat[r0 + j][cA]) = v;
        }
    }

    // ================= aff: sa = lat @ aff_w + aff_b ============================
    {
        float* wa = &wsh[0][0];                      // flat 1024 floats (wsh free now)
        wa[t] = aw[t];
        wa[512 + t] = aw[512 + t];
        __syncthreads();                             // wa + lat writes visible
        if (t < 256) {
            int r = t >> 2, cc = t & 3;
            float s = 0.f;
            for (int k = 0; k < 256; k += 4) {
                float4 a = *reinterpret_cast<const float4*>(&lat[r][k]);
                s = fmaf(a.x, wa[(k + 0) * 4 + cc], s);
                s = fmaf(a.y, wa[(k + 1) * 4 + cc], s);
                s = fmaf(a.z, wa[(k + 2) * 4 + cc], s);
                s = fmaf(a.w, wa[(k + 3) * 4 + cc], s);
            }
            sa_s[r][cc] = s + ab[cc];
        }
        __syncthreads();
    }
    float x = 0.f;
    if (t < 64) x = t_in[row0 + t] * expf(sa_s[t][1]) + sa_s[t][0];

    // ======= spline: 2 passes, each stages+computes 2 layers (hi cols 0..103, lo 104..207)
    // precompute per-it staging decode (constant across kc and pass)
    int  s_kk[7], s_c[7], s_off[7];
    bool s_ishi[7], s_val[7], s_w[7];
    #pragma unroll
    for (int it = 0; it < 7; ++it) {
        int idx = it * 512 + t;
        int kk = idx / 208;
        int c  = idx - kk * 208;
        bool inr = idx < 3328;                        // 16*208
        bool ishi = c < 104;
        int cl = ishi ? c : c - 104;
        s_kk[it] = kk; s_c[it] = c;
        s_ishi[it] = ishi;
        s_val[it] = inr && (cl < 97);
        s_off[it] = kk * 97 + cl;
        s_w[it] = inr;
    }
    float sreg[7];

    for (int pass = 0; pass < 2; ++pass) {
        const int hi = (pass == 0) ? 3 : 1;
        const int lo = hi - 1;
        const int hibase = hi * 24832;                // 256*97
        const int lobase = lo * 24832;

        #pragma unroll
        for (int j = 0; j < 8; ++j)
            #pragma unroll
            for (int i = 0; i < 4; ++i) acc[j][i] = 0.f;

        // prologue: load chunk 0
        #pragma unroll
        for (int it = 0; it < 7; ++it) {
            float v = 0.f;
            if (s_val[it]) v = sw[(size_t)((s_ishi[it] ? hibase : lobase) + s_off[it])];
            sreg[it] = v;
        }

        for (int kc = 0; kc < 16; ++kc) {
            __syncthreads();
            #pragma unroll
            for (int it = 0; it < 7; ++it)
                if (s_w[it]) wsh[s_kk[it]][s_c[it]] = sreg[it];
            __syncthreads();
            if (kc < 15) {
                #pragma unroll
                for (int it = 0; it < 7; ++it) {
                    float v = 0.f;
                    if (s_val[it])
                        v = sw[(size_t)((s_ishi[it] ? hibase : lobase) + (kc + 1) * 1552 + s_off[it])];
                    sreg[it] = v;
                }
            }
            if (tc < 52) {
                #pragma unroll
                for (int k4 = 0; k4 < 4; ++k4) {
                    float a[8][4];
                    #pragma unroll
                    for (int j = 0; j < 8; ++j)
                        *reinterpret_cast<float4*>(&a[j][0]) =
                            *reinterpret_cast<const float4*>(&lat[r0 + j][kc * 16 + k4 * 4]);
                    #pragma unroll
                    for (int s = 0; s < 4; ++s) {
                        float b[4];
                        *reinterpret_cast<float4*>(b) = *reinterpret_cast<const float4*>(&wsh[k4 * 4 + s][cA]);
                        #pragma unroll
                        for (int j = 0; j < 8; ++j)
                            #pragma unroll
                            for (int i = 0; i < 4; ++i)
                                acc[j][i] = fmaf(a[j][s], b[i], acc[j][i]);
                    }
                }
            }
        }
        // write params (hi -> pbuf[r][0..96], lo -> pbuf[r][104..200])
        if (tc < 52) {
            #pragma unroll
            for (int j = 0; j < 8; ++j)
                #pragma unroll
                for (int i = 0; i < 4; ++i) {
                    int c = cA + i;
                    if (c < 104) {
                        if (c < 97) pbuf[r0 + j][c] = acc[j][i] + sb[hi * 97 + c];
                    } else {
                        int cl = c - 104;
                        if (cl < 97) pbuf[r0 + j][104 + cl] = acc[j][i] + sb[lo * 97 + cl];
                    }
                }
        }
        __syncthreads();
        if (t < 64) {
            x = rqs_eval(x, &pbuf[t][0]);      // layer hi first (chain order)
            x = rqs_eval(x, &pbuf[t][104]);    // then layer lo
        }
    }

    // ---- f2 affine + normal CDF ----
    if (t < 64) {
        float xf = x * expf(sa_s[t][3]) + sa_s[t][2];
        out[row0 + t] = 0.5f * (1.0f + erff(xf * 0.70710678118f));
    }
}

extern "C" void kernel_launch(void* const* d_in, const int* in_sizes, int n_in,
                              void* d_out, int out_size, void* d_ws, size_t ws_size,
                              hipStream_t stream) {
    const float* cond = (const float*)d_in[0];
    const float* t_in = (const float*)d_in[1];
    const float* w1   = (const float*)d_in[2];
    const float* b1   = (const float*)d_in[3];
    const float* w2   = (const float*)d_in[4];
    const float* b2   = (const float*)d_in[5];
    const float* sw   = (const float*)d_in[6];
    const float* sb   = (const float*)d_in[7];
    const float* aw   = (const float*)d_in[8];
    const float* ab   = (const float*)d_in[9];
    float* out = (float*)d_out;

    const int B = out_size;            // 262144
    const int nblocks = B / 64;        // 4096
    condflow_kernel<<<dim3(nblocks), dim3(512), 0, stream>>>(
        cond, t_in, w1, b1, w2, b2, sw, sb, aw, ab, out);
}

// Round 9
// 567.904 us; speedup vs baseline: 9.4942x; 3.8320x over previous
//
#include <hip/hip_runtime.h>
#include <math.h>

#define NB 32

typedef _Float16 half_t;
typedef _Float16 half8 __attribute__((ext_vector_type(8)));
typedef float f32x4 __attribute__((ext_vector_type(4)));

// fragment blob indices (each fragment = 512 half = 1 KB, lane-major: lane*8 halfs)
// B-frag: lane l holds B[k = ks*32 + (l>>4)*8 + j][n = ct*16 + (l&15)], j=0..7
// hi blob at frag f, lo blob at frag FR_TOTAL + f.
#define FR_G1  0      // ks(2)*16 + ct(16)                  -> 32 frags
#define FR_G2  32     // 32 + ks(8)*16 + ct(16)             -> 128
#define FR_SP  160    // 160 + layer*56 + ks(8)*7 + ct(7)   -> 224 (cols >=97 zero)
#define FR_AFF 384    // 384 + ks(8)                        -> 8 (cols >=4 zero)
#define FR_TOTAL 392  // hi+lo = 784 KB in d_ws

__device__ __forceinline__ void split16(float x, half_t& h, half_t& l) {
    h = (half_t)x;
    l = (half_t)(x - (float)h);
}

__global__ __launch_bounds__(64) void prep_kernel(
    const float* __restrict__ w1, const float* __restrict__ w2,
    const float* __restrict__ sw, const float* __restrict__ aw,
    half_t* __restrict__ frags)
{
    const int f = blockIdx.x;
    const int l = threadIdx.x;
    const int kl = (l >> 4) * 8;
    const int nl = l & 15;
    half8 vh, vl;
    #pragma unroll
    for (int j = 0; j < 8; ++j) {
        float w = 0.f;
        if (f < FR_G2) {
            int ks = f >> 4, ct = f & 15;
            w = w1[(ks * 32 + kl + j) * 256 + ct * 16 + nl];
        } else if (f < FR_SP) {
            int g = f - FR_G2;
            int ks = g >> 4, ct = g & 15;
            w = w2[(ks * 32 + kl + j) * 256 + ct * 16 + nl];
        } else if (f < FR_AFF) {
            int g = f - FR_SP;
            int layer = g / 56, r = g - layer * 56;
            int ks = r / 7, ct = r - ks * 7;
            int n = ct * 16 + nl;
            if (n < 97) w = sw[(size_t)layer * 24832 + (size_t)(ks * 32 + kl + j) * 97 + n];
        } else {
            int ks = f - FR_AFF;
            if (nl < 4) w = aw[(ks * 32 + kl + j) * 4 + nl];
        }
        half_t h, lo;
        split16(w, h, lo);
        vh[j] = h; vl[j] = lo;
    }
    *reinterpret_cast<half8*>(frags + (size_t)f * 512 + l * 8) = vh;
    *reinterpret_cast<half8*>(frags + (size_t)(FR_TOTAL + f) * 512 + l * 8) = vl;
}

__device__ __forceinline__ float softplus_f(float v) {
    return v > 0.f ? v + log1pf(expf(-v)) : log1pf(expf(v));
}

// p -> this row's 97 spline params in LDS; overwrites p[0..63] as scratch. (verified r3)
__device__ float rqs_eval(float x, float* p) {
    const float RMIN = -3.0f;
    const float total = 6.0f - 32.0f * 1e-5f;
    const float OFF = 0.54130903f;                // log(exp(1-1e-5)-1)

    float mw = -INFINITY, mh = -INFINITY;
    #pragma unroll
    for (int i = 0; i < NB; ++i) {
        mw = fmaxf(mw, p[i]);
        mh = fmaxf(mh, p[NB + i]);
    }
    float swd = 0.f, shd = 0.f;
    #pragma unroll
    for (int i = 0; i < NB; ++i) {
        swd += expf(p[i] - mw);
        shd += expf(p[NB + i] - mh);
    }
    float sw_scale = total / swd;
    float sh_scale = total / shd;

    float cumw = 0.f;
    int cnt = 0;
    #pragma unroll
    for (int i = 0; i < NB; ++i) {
        float wi = expf(p[i] - mw) * sw_scale + 1e-5f;
        p[i] = wi;
        cumw += wi;
        cnt += (x >= RMIN + cumw) ? 1 : 0;
        float hi = expf(p[NB + i] - mh) * sh_scale + 1e-5f;
        p[NB + i] = hi;
    }
    int idx = cnt < 31 ? cnt : 31;

    float cw = 0.f, ch = 0.f;
    #pragma unroll
    for (int i = 0; i < NB; ++i) {
        if (i < idx) { cw += p[i]; ch += p[NB + i]; }
    }
    float wk = p[idx], hk = p[NB + idx];
    float dk  = softplus_f(p[2 * NB + idx] + OFF) + 1e-5f;
    float dk1 = softplus_f(p[2 * NB + idx + 1] + OFF) + 1e-5f;

    float xk = RMIN + cw, yk = RMIN + ch;
    float z = (x - xk) / wk;
    z = fminf(fmaxf(z, 0.f), 1.f);
    float s = hk / wk;
    float z1 = z * (1.f - z);
    float num = hk * (s * z * z + dk * z1);
    float den = s + (dk1 + dk - 2.f * s) * z1;
    float y = yk + num / den;
    return (x < -3.0f || x > 3.0f) ? x : y;
}

#define LT 264    // lat16 row stride in halfs (528B)
#define CT 136    // cond16 row stride in halfs (272B)

__global__ __launch_bounds__(512, 1) void condflow_kernel(
    const float* __restrict__ cond, const float* __restrict__ t_in,
    const float* __restrict__ b1, const float* __restrict__ b2,
    const float* __restrict__ sb, const float* __restrict__ ab,
    const half_t* __restrict__ frags,
    float* __restrict__ out)
{
    __shared__ half_t lat16h[64 * LT];    // 33792 B
    __shared__ half_t lat16l[64 * LT];    // 33792 B
    __shared__ float pbuf[64][137];       // 35072 B (cond16 h+l overlay, then spline params)
    __shared__ float sa_s[64][4];         // 1024 B   -> ~102 KB total
    half_t* cond16h = reinterpret_cast<half_t*>(&pbuf[0][0]);            // [64][CT]
    half_t* cond16l = cond16h + 64 * CT;                                  // [64][CT]

    const int t    = threadIdx.x;
    const int row0 = blockIdx.x * 64;
    const int wid  = t >> 6;
    const int lane = t & 63;
    const int q    = lane >> 4;
    const int nl   = lane & 15;
    const half_t* fr_lo = frags + (size_t)FR_TOTAL * 512;

    // ---- stage cond [64][64] -> f16 hi/lo LDS ----
    {
        int r = t >> 3, c0 = (t & 7) * 8;
        const float* src = cond + (size_t)(row0 + r) * 64 + c0;
        float4 v0 = *reinterpret_cast<const float4*>(src);
        float4 v1 = *reinterpret_cast<const float4*>(src + 4);
        half8 hh, hl;
        float vv[8] = {v0.x, v0.y, v0.z, v0.w, v1.x, v1.y, v1.z, v1.w};
        #pragma unroll
        for (int j = 0; j < 8; ++j) { half_t h, l; split16(vv[j], h, l); hh[j] = h; hl[j] = l; }
        *reinterpret_cast<half8*>(cond16h + r * CT + c0) = hh;
        *reinterpret_cast<half8*>(cond16l + r * CT + c0) = hl;
    }
    __syncthreads();

    // ---- GEMM1: latent1 = relu(cond @ w1 + b1), K=64. wave -> cts {2wid, 2wid+1} ----
    {
        f32x4 c[4][2];
        #pragma unroll
        for (int rt = 0; rt < 4; ++rt)
            #pragma unroll
            for (int ic = 0; ic < 2; ++ic) c[rt][ic] = f32x4{0.f, 0.f, 0.f, 0.f};

        #pragma unroll
        for (int ks = 0; ks < 2; ++ks) {
            half8 ah[4], al[4];
            #pragma unroll
            for (int rt = 0; rt < 4; ++rt) {
                int off = (rt * 16 + nl) * CT + ks * 32 + q * 8;
                ah[rt] = *reinterpret_cast<const half8*>(cond16h + off);
                al[rt] = *reinterpret_cast<const half8*>(cond16l + off);
            }
            #pragma unroll
            for (int ic = 0; ic < 2; ++ic) {
                int fidx = FR_G1 + ks * 16 + (wid * 2 + ic);
                half8 bh = *reinterpret_cast<const half8*>(frags + (size_t)fidx * 512 + lane * 8);
                half8 bl = *reinterpret_cast<const half8*>(fr_lo + (size_t)fidx * 512 + lane * 8);
                #pragma unroll
                for (int rt = 0; rt < 4; ++rt) {
                    c[rt][ic] = __builtin_amdgcn_mfma_f32_16x16x32_f16(ah[rt], bh, c[rt][ic], 0, 0, 0);
                    c[rt][ic] = __builtin_amdgcn_mfma_f32_16x16x32_f16(al[rt], bh, c[rt][ic], 0, 0, 0);
                    c[rt][ic] = __builtin_amdgcn_mfma_f32_16x16x32_f16(ah[rt], bl, c[rt][ic], 0, 0, 0);
                }
            }
        }
        // epilogue: relu+bias -> lat16 hi/lo. C/D: col=nl, row=q*4+reg
        #pragma unroll
        for (int ic = 0; ic < 2; ++ic) {
            int col = (wid * 2 + ic) * 16 + nl;
            float bv = b1[col];
            #pragma unroll
            for (int rt = 0; rt < 4; ++rt)
                #pragma unroll
                for (int reg = 0; reg < 4; ++reg) {
                    float y = fmaxf(c[rt][ic][reg] + bv, 0.f);
                    half_t h, l; split16(y, h, l);
                    int off = (rt * 16 + q * 4 + reg) * LT + col;
                    lat16h[off] = h; lat16l[off] = l;
                }
        }
    }
    __syncthreads();

    // ---- GEMM2: latent2 = relu(latent1 @ w2 + b2), K=256, in place ----
    {
        f32x4 c[4][2];
        #pragma unroll
        for (int rt = 0; rt < 4; ++rt)
            #pragma unroll
            for (int ic = 0; ic < 2; ++ic) c[rt][ic] = f32x4{0.f, 0.f, 0.f, 0.f};

        #pragma unroll
        for (int ks = 0; ks < 8; ++ks) {
            half8 ah[4], al[4];
            #pragma unroll
            for (int rt = 0; rt < 4; ++rt) {
                int off = (rt * 16 + nl) * LT + ks * 32 + q * 8;
                ah[rt] = *reinterpret_cast<const half8*>(lat16h + off);
                al[rt] = *reinterpret_cast<const half8*>(lat16l + off);
            }
            #pragma unroll
            for (int ic = 0; ic < 2; ++ic) {
                int fidx = FR_G2 + ks * 16 + (wid * 2 + ic);
                half8 bh = *reinterpret_cast<const half8*>(frags + (size_t)fidx * 512 + lane * 8);
                half8 bl = *reinterpret_cast<const half8*>(fr_lo + (size_t)fidx * 512 + lane * 8);
                #pragma unroll
                for (int rt = 0; rt < 4; ++rt) {
                    c[rt][ic] = __builtin_amdgcn_mfma_f32_16x16x32_f16(ah[rt], bh, c[rt][ic], 0, 0, 0);
                    c[rt][ic] = __builtin_amdgcn_mfma_f32_16x16x32_f16(al[rt], bh, c[rt][ic], 0, 0, 0);
                    c[rt][ic] = __builtin_amdgcn_mfma_f32_16x16x32_f16(ah[rt], bl, c[rt][ic], 0, 0, 0);
                }
            }
        }
        __syncthreads();   // ALL latent1 reads complete before overwrite
        #pragma unroll
        for (int ic = 0; ic < 2; ++ic) {
            int col = (wid * 2 + ic) * 16 + nl;
            float bv = b2[col];
            #pragma unroll
            for (int rt = 0; rt < 4; ++rt)
                #pragma unroll
                for (int reg = 0; reg < 4; ++reg) {
                    float y = fmaxf(c[rt][ic][reg] + bv, 0.f);
                    half_t h, l; split16(y, h, l);
                    int off = (rt * 16 + q * 4 + reg) * LT + col;
                    lat16h[off] = h; lat16l[off] = l;
                }
        }
    }
    __syncthreads();

    // ---- aff (wave 0 only; other waves run ahead into spline K-loop) ----
    if (wid == 0) {
        #pragma unroll
        for (int rt = 0; rt < 4; ++rt) {
            f32x4 c0 = f32x4{0.f, 0.f, 0.f, 0.f};
            #pragma unroll
            for (int ks = 0; ks < 8; ++ks) {
                int off = (rt * 16 + nl) * LT + ks * 32 + q * 8;
                half8 ah = *reinterpret_cast<const half8*>(lat16h + off);
                half8 al = *reinterpret_cast<const half8*>(lat16l + off);
                half8 bh = *reinterpret_cast<const half8*>(frags + (size_t)(FR_AFF + ks) * 512 + lane * 8);
                half8 bl = *reinterpret_cast<const half8*>(fr_lo + (size_t)(FR_AFF + ks) * 512 + lane * 8);
                c0 = __builtin_amdgcn_mfma_f32_16x16x32_f16(ah, bh, c0, 0, 0, 0);
                c0 = __builtin_amdgcn_mfma_f32_16x16x32_f16(al, bh, c0, 0, 0, 0);
                c0 = __builtin_amdgcn_mfma_f32_16x16x32_f16(ah, bl, c0, 0, 0, 0);
            }
            if (nl < 4) {
                #pragma unroll
                for (int reg = 0; reg < 4; ++reg)
                    sa_s[rt * 16 + q * 4 + reg][nl] = c0[reg] + ab[nl];
            }
        }
    }
    float x = 0.f;
    if (t < 64) x = t_in[row0 + t] * expf(sa_s[t][1]) + sa_s[t][0];   // wave 0 only

    // ---- spline chain, layer 3 -> 0. waves 0..6 -> col-tile wid (N padded to 112) ----
    for (int layer = 3; layer >= 0; --layer) {
        f32x4 c[4];
        #pragma unroll
        for (int rt = 0; rt < 4; ++rt) c[rt] = f32x4{0.f, 0.f, 0.f, 0.f};
        if (wid < 7) {
            #pragma unroll
            for (int ks = 0; ks < 8; ++ks) {
                half8 ah[4], al[4];
                #pragma unroll
                for (int rt = 0; rt < 4; ++rt) {
                    int off = (rt * 16 + nl) * LT + ks * 32 + q * 8;
                    ah[rt] = *reinterpret_cast<const half8*>(lat16h + off);
                    al[rt] = *reinterpret_cast<const half8*>(lat16l + off);
                }
                int fidx = FR_SP + layer * 56 + ks * 7 + wid;
                half8 bh = *reinterpret_cast<const half8*>(frags + (size_t)fidx * 512 + lane * 8);
                half8 bl = *reinterpret_cast<const half8*>(fr_lo + (size_t)fidx * 512 + lane * 8);
                #pragma unroll
                for (int rt = 0; rt < 4; ++rt) {
                    c[rt] = __builtin_amdgcn_mfma_f32_16x16x32_f16(ah[rt], bh, c[rt], 0, 0, 0);
                    c[rt] = __builtin_amdgcn_mfma_f32_16x16x32_f16(al[rt], bh, c[rt], 0, 0, 0);
                    c[rt] = __builtin_amdgcn_mfma_f32_16x16x32_f16(ah[rt], bl, c[rt], 0, 0, 0);
                }
            }
        }
        __syncthreads();          // prev layer's rqs done with pbuf before overwrite
        if (wid < 7) {
            int n0 = wid * 16 + nl;                       // 0..111 < 137
            float sbv = (n0 < 97) ? sb[layer * 97 + n0] : 0.f;
            #pragma unroll
            for (int rt = 0; rt < 4; ++rt)
                #pragma unroll
                for (int reg = 0; reg < 4; ++reg)
                    pbuf[rt * 16 + q * 4 + reg][n0] = c[rt][reg] + sbv;
        }
        __syncthreads();
        if (t < 64) x = rqs_eval(x, &pbuf[t][0]);         // wave 0; others run ahead
    }

    // ---- f2 affine + normal CDF ----
    if (t < 64) {
        float xf = x * expf(sa_s[t][3]) + sa_s[t][2];
        out[row0 + t] = 0.5f * (1.0f + erff(xf * 0.70710678118f));
    }
}

extern "C" void kernel_launch(void* const* d_in, const int* in_sizes, int n_in,
                              void* d_out, int out_size, void* d_ws, size_t ws_size,
                              hipStream_t stream) {
    const float* cond = (const float*)d_in[0];
    const float* t_in = (const float*)d_in[1];
    const float* w1   = (const float*)d_in[2];
    const float* b1   = (const float*)d_in[3];
    const float* w2   = (const float*)d_in[4];
    const float* b2   = (const float*)d_in[5];
    const float* sw   = (const float*)d_in[6];
    const float* sb   = (const float*)d_in[7];
    const float* aw   = (const float*)d_in[8];
    const float* ab   = (const float*)d_in[9];
    float* out = (float*)d_out;

    half_t* frags = (half_t*)d_ws;        // needs 784 KB of workspace (hi + lo blobs)

    prep_kernel<<<dim3(FR_TOTAL), dim3(64), 0, stream>>>(w1, w2, sw, aw, frags);

    const int B = out_size;               // 262144
    const int nblocks = B / 64;           // 4096
    condflow_kernel<<<dim3(nblocks), dim3(512), 0, stream>>>(
        cond, t_in, b1, b2, sb, ab, frags, out);
}